// Round 10
// baseline (131.700 us; speedup 1.0000x reference)
//
#include <hip/hip_runtime.h>
#include <hip/hip_bf16.h>

// GraphLayer: B=8, K=128, D=128, TPE=64, PPE=64, HEADS=8, G=16
// d_out = [v_out (8*128*128 f32) | e_value (8*16384*128 f32)]
//
// Round 10: round-7 k_edge K-loop verbatim (16 x 2-kstep phases, 2x8KB dbuf,
// 51.2KB LDS, 3 blocks/CU — proven 53.8us) + round-9's inline attention
// epilogue (verified correct) replacing the separate k_atten launch.

typedef __attribute__((ext_vector_type(8)))  short bh8;   // 8 x bf16 (as short)
typedef __attribute__((ext_vector_type(16))) float f16v;  // MFMA 32x32 accum
typedef __attribute__((ext_vector_type(4)))  float f4v;

__device__ __forceinline__ unsigned short f2bf(float f) {
  unsigned u = __builtin_bit_cast(unsigned, f);
  u += 0x7fffu + ((u >> 16) & 1u);          // RNE
  return (unsigned short)(u >> 16);
}
__device__ __forceinline__ float silu_f(float x) {
  float e = __builtin_amdgcn_exp2f(x * -1.44269504088896f);   // e^-x
  return x * __builtin_amdgcn_rcpf(1.f + e);
}
__device__ __forceinline__ bh8 cvt8(f4v x, f4v y) {
  bh8 a;
  a[0] = (short)f2bf(x[0]); a[1] = (short)f2bf(x[1]);
  a[2] = (short)f2bf(x[2]); a[3] = (short)f2bf(x[3]);
  a[4] = (short)f2bf(y[0]); a[5] = (short)f2bf(y[1]);
  a[6] = (short)f2bf(y[2]); a[7] = (short)f2bf(y[3]);
  return a;
}
typedef const __attribute__((address_space(1))) unsigned int gq_t;
typedef __attribute__((address_space(3))) unsigned int lq_t;
__device__ __forceinline__ void gload_lds16(const void* g, void* l) {
  // dest is wave-uniform base; HW adds lane*16. src is per-lane.
  __builtin_amdgcn_global_load_lds((gq_t*)g, (lq_t*)l, 16, 0, 0);
}

// ---------- prep: weight frags (3) + tc = t_pe@W_epe[128:192] + b_epe ----------
// frag idx = ((ni*ksteps + ks)*64 + lane)*8 + jj ; col n = ni*32+(l&31), k = ks*16+(l>>5)*8+jj
__device__ __forceinline__ void wfrag_work(const float* __restrict__ W,
                                           short* __restrict__ dst, int kdim,
                                           int blk, int nblk) {
  int ksteps = kdim >> 4;
  int total  = kdim * 128;
  for (int idx = blk * 256 + threadIdx.x; idx < total; idx += nblk * 256) {
    int jj = idx & 7;
    int l  = (idx >> 3) & 63;
    int rest = idx >> 9;
    int ks = rest % ksteps;
    int ni = rest / ksteps;
    int n  = ni * 32 + (l & 31);
    int kk = ks * 16 + ((l >> 5) << 3) + jj;
    dst[idx] = (short)f2bf(W[kk * 128 + n]);
  }
}
__global__ void k_prep(const float* __restrict__ W_epe, short* __restrict__ wf1,
                       const float* __restrict__ W_ev1, short* __restrict__ wf2,
                       const float* __restrict__ W_ev2, short* __restrict__ wf3,
                       const float* __restrict__ tpe, const float* __restrict__ bepe,
                       float* __restrict__ tc) {
  int blk = blockIdx.x;
  if (blk < 64)       wfrag_work(W_epe, wf1, 128, blk, 64);
  else if (blk < 192) wfrag_work(W_ev1 + 128 * 128, wf2, 256, blk - 64, 128);
  else if (blk < 256) wfrag_work(W_ev2, wf3, 128, blk - 192, 64);
  else {
    int t = threadIdx.x;
    int b = (blk - 256) * 2 + (t >> 7);
    int n = t & 127;
    float a = bepe[n];
    for (int k2 = 0; k2 < 64; ++k2) a += tpe[b * 64 + k2] * W_epe[(128 + k2) * 128 + n];
    tc[b * 128 + n] = a;
  }
}

// ---------- node MLPs: v = silu(x@Wv+b); q,k,self,evi from v ----------
__global__ __launch_bounds__(128) void k_node(
    const float* __restrict__ vfeat, const float* __restrict__ ppe,
    const float* __restrict__ tpe, const float* __restrict__ Wv,
    const float* __restrict__ bv, const float* __restrict__ Wq,
    const float* __restrict__ bq, const float* __restrict__ Wk,
    const float* __restrict__ bk, const float* __restrict__ Ws,
    const float* __restrict__ bs, const float* __restrict__ We,
    const float* __restrict__ be, unsigned short* __restrict__ vb16,
    float* __restrict__ q, float* __restrict__ kb, float* __restrict__ sa,
    float* __restrict__ evi) {
  __shared__ float x[4][256];
  __shared__ float xv[4][128];
  const int r0 = blockIdx.x * 4;
  const int b  = r0 >> 7;
  const int t  = threadIdx.x;
  #pragma unroll
  for (int rr = 0; rr < 4; ++rr) {
    int row = r0 + rr;
    x[rr][t] = vfeat[row * 128 + t];
    int c = t + 128;
    x[rr][c] = (c < 192) ? ppe[row * 64 + (c - 128)] : tpe[b * 64 + (c - 192)];
  }
  __syncthreads();
  float av[4];
  const float bvv = bv[t];
  #pragma unroll
  for (int rr = 0; rr < 4; ++rr) av[rr] = bvv;
  for (int k4 = 0; k4 < 256; k4 += 4) {
    f4v xx0 = *(const f4v*)&x[0][k4];
    f4v xx1 = *(const f4v*)&x[1][k4];
    f4v xx2 = *(const f4v*)&x[2][k4];
    f4v xx3 = *(const f4v*)&x[3][k4];
    #pragma unroll
    for (int u = 0; u < 4; ++u) {
      float w = Wv[(k4 + u) * 128 + t];
      av[0] += xx0[u] * w; av[1] += xx1[u] * w;
      av[2] += xx2[u] * w; av[3] += xx3[u] * w;
    }
  }
  #pragma unroll
  for (int rr = 0; rr < 4; ++rr) {
    float s = silu_f(av[rr]);
    vb16[(r0 + rr) * 128 + t] = f2bf(s);
    xv[rr][t] = s;
  }
  __syncthreads();
  float aq[4], ak[4], as_[4], ae[4];
  const float bqv = bq[t], bkv = bk[t], bsv = bs[t], bev = be[t];
  #pragma unroll
  for (int rr = 0; rr < 4; ++rr) { aq[rr] = bqv; ak[rr] = bkv; as_[rr] = bsv; ae[rr] = bev; }
  for (int k4 = 0; k4 < 128; k4 += 4) {
    f4v xx0 = *(const f4v*)&xv[0][k4];
    f4v xx1 = *(const f4v*)&xv[1][k4];
    f4v xx2 = *(const f4v*)&xv[2][k4];
    f4v xx3 = *(const f4v*)&xv[3][k4];
    #pragma unroll
    for (int u = 0; u < 4; ++u) {
      float wq = Wq[(k4 + u) * 128 + t];
      float wk = Wk[(k4 + u) * 128 + t];
      float ws2 = Ws[(k4 + u) * 128 + t];
      float we2 = We[(k4 + u) * 128 + t];
      aq[0] += xx0[u] * wq; aq[1] += xx1[u] * wq; aq[2] += xx2[u] * wq; aq[3] += xx3[u] * wq;
      ak[0] += xx0[u] * wk; ak[1] += xx1[u] * wk; ak[2] += xx2[u] * wk; ak[3] += xx3[u] * wk;
      as_[0] += xx0[u] * ws2; as_[1] += xx1[u] * ws2; as_[2] += xx2[u] * ws2; as_[3] += xx3[u] * ws2;
      ae[0] += xx0[u] * we2; ae[1] += xx1[u] * we2; ae[2] += xx2[u] * we2; ae[3] += xx3[u] * we2;
    }
  }
  #pragma unroll
  for (int rr = 0; rr < 4; ++rr) {
    q[(r0 + rr) * 128 + t]  = aq[rr];
    kb[(r0 + rr) * 128 + t] = ak[rr];
    sa[(r0 + rr) * 128 + t] = silu_f(as_[rr]);
    evi[(r0 + rr) * 128 + t] = ae[rr];   // v_i@W_ev1[0:128] + b_ev1 (no silu)
  }
}

// ---------- fused edge chain + inline attention + aggregation ----------
// block=(b,i); 128 j; 4 waves x (32 rows x 128 cols); 16 phases x 2 ksteps
// (round-7 proven loop). Attention inlined in the epilogue (round-9 proven).
__global__ __launch_bounds__(256) void k_edge(
    const float* __restrict__ ef, const unsigned short* __restrict__ vb,
    const short* __restrict__ wf1, const short* __restrict__ wf2,
    const short* __restrict__ wf3, const float* __restrict__ tc,
    const float* __restrict__ evic, const float* __restrict__ bev2,
    const float* __restrict__ qbuf, const float* __restrict__ kbuf,
    const float* __restrict__ sab, float* __restrict__ oute,
    float* __restrict__ vfb) {
  __shared__ __align__(16) unsigned short wbuf0[4096];      // 8KB chunk buffer
  __shared__ __align__(16) unsigned short wbuf1[4096];      // 8KB chunk buffer
  __shared__ __align__(16) unsigned short hbuf[128 * 136];  // 34816B, 272B stride
  const int bi  = blockIdx.x;
  const int b   = bi >> 7;
  const int tid = threadIdx.x;
  const int w   = tid >> 6;
  const int l   = tid & 63;
  const int row = w * 32 + (l & 31);          // j index (A rows)
  const int kh  = (l >> 5) << 3;              // 0 or 8
  const int cb  = l & 31;                     // C/D col base
  const int rb  = w * 32 + ((l >> 5) << 2);   // C/D row base

  const float* efr = ef + (size_t)(bi * 128 + row) * 128;
  const unsigned short* vj = vb + (size_t)(b * 128 + row) * 128;

  // stage one 2-kstep chunk (8 frags x 1KB) into dstb
  auto stage2 = [&](const short* wfp, int KST, int kc, unsigned short* dstb) {
    #pragma unroll
    for (int it = 0; it < 2; ++it) {
      int g  = it * 4 + w;            // slot g: ni=g&3(=w), kso=g>>2(=it)
      int ni = g & 3, kso = g >> 2;
      const short* src = wfp + ((size_t)(ni * KST + kc * 2 + kso) * 64 + l) * 8;
      gload_lds16(src, dstb + g * 512);
    }
  };
  f16v acc[4];
  auto compute2 = [&](const unsigned short* ws2, bh8 aa, bh8 ab2) {
    #pragma unroll
    for (int ni = 0; ni < 4; ++ni) {
      bh8 b0 = *(const bh8*)&ws2[ni * 512 + l * 8];
      acc[ni] = __builtin_amdgcn_mfma_f32_32x32x16_bf16(aa, b0, acc[ni], 0, 0, 0);
    }
    #pragma unroll
    for (int ni = 0; ni < 4; ++ni) {
      bh8 b1 = *(const bh8*)&ws2[(4 + ni) * 512 + l * 8];
      acc[ni] = __builtin_amdgcn_mfma_f32_32x32x16_bf16(ab2, b1, acc[ni], 0, 0, 0);
    }
  };
  // A-operand for global kstep t: 0-7 e_f, 8-15 v_j, 16-23 h1(LDS), 24-31 h2(LDS)
  auto ldA = [&](int t) -> bh8 {
    if (t < 8) {
      const float* p = efr + t * 16 + kh;
      f4v x0 = *(const f4v*)p;
      f4v x1 = *(const f4v*)(p + 4);
      return cvt8(x0, x1);
    } else if (t < 16) {
      return *(const bh8*)(vj + (t - 8) * 16 + kh);
    } else if (t < 24) {
      return *(const bh8*)&hbuf[row * 136 + (t - 16) * 16 + kh];
    } else {
      return *(const bh8*)&hbuf[row * 136 + (t - 24) * 16 + kh];
    }
  };

  float tin[4], ein[4];
  #pragma unroll
  for (int ni = 0; ni < 4; ++ni) {
    tin[ni] = tc[b * 128 + ni * 32 + cb];
    ein[ni] = evic[bi * 128 + ni * 32 + cb];
  }
  #pragma unroll
  for (int ni = 0; ni < 4; ++ni)
    #pragma unroll
    for (int r = 0; r < 16; ++r) acc[ni][r] = tin[ni];

  // prologue: chunk 0 + A(0,1)
  stage2(wf1, 8, 0, wbuf0);
  bh8 a0c = ldA(0), a1c = ldA(1);
  __syncthreads();

  #pragma unroll
  for (int c = 0; c < 16; ++c) {
    if (c + 1 < 16) {
      const short* wp; int KST, kc;
      if (c + 1 < 4)       { wp = wf1; KST = 8;  kc = c + 1; }
      else if (c + 1 < 12) { wp = wf2; KST = 16; kc = c + 1 - 4; }
      else                 { wp = wf3; KST = 8;  kc = c + 1 - 12; }
      stage2(wp, KST, kc, (c & 1) ? wbuf0 : wbuf1);
    }
    bh8 a0n, a1n;
    const bool pre = (c + 1 < 16) && (c != 11);   // c=11->12 crosses h2 epi
    if (pre) { a0n = ldA(2 * (c + 1)); a1n = ldA(2 * (c + 1) + 1); }
    compute2((c & 1) ? wbuf1 : wbuf0, a0c, a1c);
    if (c == 3) {            // h1 -> hbuf (same-wave rows); acc := evic
      #pragma unroll
      for (int ni = 0; ni < 4; ++ni) {
        int n = ni * 32 + cb;
        #pragma unroll
        for (int r = 0; r < 16; ++r) {
          int rj = rb + (r & 3) + ((r >> 2) << 3);
          hbuf[rj * 136 + n] = f2bf(silu_f(acc[ni][r]));
          acc[ni][r] = ein[ni];
        }
      }
    }
    if (c == 11) {           // h2 -> hbuf; acc := 0; L3 A direct from hbuf
      #pragma unroll
      for (int ni = 0; ni < 4; ++ni) {
        int n = ni * 32 + cb;
        #pragma unroll
        for (int r = 0; r < 16; ++r) {
          int rj = rb + (r & 3) + ((r >> 2) << 3);
          hbuf[rj * 136 + n] = f2bf(silu_f(acc[ni][r]));
          acc[ni][r] = 0.f;
        }
      }
      a0c = ldA(24); a1c = ldA(25);
    } else if (pre) {
      a0c = a0n; a1c = a1n;
    }
    __syncthreads();
  }

  // ===== e_value store (+bias)
  #pragma unroll
  for (int ni = 0; ni < 4; ++ni) {
    int n = ni * 32 + cb;
    float bv = bev2[n];
    #pragma unroll
    for (int r = 0; r < 16; ++r) {
      int rj = rb + (r & 3) + ((r >> 2) << 3);
      acc[ni][r] += bv;
      oute[(size_t)(bi * 128 + rj) * 128 + n] = acc[ni][r];
    }
  }

  // ===== inline attention (round-9 verified) + aggregation
  __syncthreads();                       // all hbuf reads done before reuse
  float* arena = (float*)hbuf;
  float* qr   = arena;                   // 128
  float* s    = arena + 128;             // 128*17
  float* red  = arena + 2304;            // 8*17
  float* gmax = arena + 2448;            // 16
  float* gsum = arena + 2464;            // 16
  float* attf = arena + 2560;            // 2048 (transposed atten)
  float* aggl = arena + 4608;            // 512
  const float sc = 0.20412414523193154f; // 1/sqrt(24)
  float loc[16];
  if (tid < 128) qr[tid] = qbuf[(size_t)bi * 128 + tid];
  __syncthreads();
  if (tid < 128) {
    const float* krow = kbuf + (size_t)(b * 128 + tid) * 128;
    #pragma unroll
    for (int g = 0; g < 16; ++g) {
      f4v k0 = *(const f4v*)&krow[g * 8];
      f4v k1 = *(const f4v*)&krow[g * 8 + 4];
      float a = 0.f;
      #pragma unroll
      for (int h = 0; h < 4; ++h) a += qr[g * 8 + h] * k0[h] + qr[g * 8 + 4 + h] * k1[h];
      loc[g] = a * sc;
      s[tid * 17 + g] = loc[g];
    }
  }
  __syncthreads();
  if (tid < 128) {
    int g = tid & 15, cp = tid >> 4;
    float m = -1e30f;
    for (int j2 = cp * 16; j2 < cp * 16 + 16; ++j2) m = fmaxf(m, s[j2 * 17 + g]);
    red[cp * 17 + g] = m;
  }
  __syncthreads();
  if (tid < 16) {
    float m = red[tid];
    #pragma unroll
    for (int cp = 1; cp < 8; ++cp) m = fmaxf(m, red[cp * 17 + tid]);
    gmax[tid] = m;
  }
  __syncthreads();
  if (tid < 128) {
    #pragma unroll
    for (int g = 0; g < 16; ++g) {
      loc[g] = __builtin_amdgcn_exp2f((loc[g] - gmax[g]) * 1.44269504088896f);
      s[tid * 17 + g] = loc[g];
    }
  }
  __syncthreads();
  if (tid < 128) {
    int g = tid & 15, cp = tid >> 4;
    float m = 0.f;
    for (int j2 = cp * 16; j2 < cp * 16 + 16; ++j2) m += s[j2 * 17 + g];
    red[cp * 17 + g] = m;
  }
  __syncthreads();
  if (tid < 16) {
    float m = 0.f;
    #pragma unroll
    for (int cp = 0; cp < 8; ++cp) m += red[cp * 17 + tid];
    gsum[tid] = m;
  }
  __syncthreads();
  if (tid < 128) {    // attf[j][ (g&3)*4 + (g>>2) ] = atten[j][g]
    #pragma unroll
    for (int g = 0; g < 16; ++g) {
      float v = loc[g] * __builtin_amdgcn_rcpf(gsum[g]);
      attf[tid * 16 + (g & 3) * 4 + (g >> 2)] = v;
    }
  }
  float sav = 0.f;
  if (tid < 128) sav = sab[(size_t)bi * 128 + tid];
  __syncthreads();
  float p0 = 0.f, p1 = 0.f, p2 = 0.f, p3 = 0.f;
  const int gl = (l & 31) >> 3;
  #pragma unroll
  for (int r = 0; r < 16; ++r) {
    int rj = rb + (r & 3) + ((r >> 2) << 3);
    f4v av = *(const f4v*)&attf[rj * 16 + gl * 4];
    p0 += av[0] * acc[0][r]; p1 += av[1] * acc[1][r];
    p2 += av[2] * acc[2][r]; p3 += av[3] * acc[3][r];
  }
  p0 += __shfl_xor(p0, 32); p1 += __shfl_xor(p1, 32);
  p2 += __shfl_xor(p2, 32); p3 += __shfl_xor(p3, 32);
  if (l < 32) {
    aggl[w * 128 +  0 + l] = p0;
    aggl[w * 128 + 32 + l] = p1;
    aggl[w * 128 + 64 + l] = p2;
    aggl[w * 128 + 96 + l] = p3;
  }
  __syncthreads();
  if (tid < 128) {
    vfb[(size_t)bi * 128 + tid] =
        aggl[tid] + aggl[128 + tid] + aggl[256 + tid] + aggl[384 + tid] + sav;
  }
}

// ---------- max-pool over i (2 stage) ----------
__global__ void k_pool1(const float* __restrict__ vfb, float* __restrict__ pm) {
  const int b = blockIdx.x >> 3, c = blockIdx.x & 7;
  const int t = threadIdx.x;
  float m = -1e30f;
  for (int i2 = c * 16; i2 < c * 16 + 16; ++i2)
    m = fmaxf(m, vfb[(size_t)(b * 128 + i2) * 128 + t]);
  pm[(size_t)blockIdx.x * 128 + t] = m;
}
__global__ void k_pool2(const float* __restrict__ pm, float* __restrict__ pool) {
  const int b = blockIdx.x;
  const int t = threadIdx.x;
  float m = -1e30f;
  #pragma unroll
  for (int c = 0; c < 8; ++c) m = fmaxf(m, pm[(size_t)(b * 8 + c) * 128 + t]);
  pool[b * 128 + t] = m;
}

// ---------- out MLP: v_out = silu([vf|pool] @ W_out + b) ----------
__global__ __launch_bounds__(128) void k_out(
    const float* __restrict__ vfb, const float* __restrict__ pool,
    const float* __restrict__ W, const float* __restrict__ bias,
    float* __restrict__ vout) {
  __shared__ float x[4][256];
  const int r0 = blockIdx.x * 4;
  const int b  = r0 >> 7;
  const int t  = threadIdx.x;
  #pragma unroll
  for (int rr = 0; rr < 4; ++rr) {
    x[rr][t]       = vfb[(r0 + rr) * 128 + t];
    x[rr][t + 128] = pool[b * 128 + t];
  }
  __syncthreads();
  float acc[4];
  const float bv = bias[t];
  #pragma unroll
  for (int rr = 0; rr < 4; ++rr) acc[rr] = bv;
  for (int k4 = 0; k4 < 256; k4 += 4) {
    f4v xx0 = *(const f4v*)&x[0][k4];
    f4v xx1 = *(const f4v*)&x[1][k4];
    f4v xx2 = *(const f4v*)&x[2][k4];
    f4v xx3 = *(const f4v*)&x[3][k4];
    #pragma unroll
    for (int u = 0; u < 4; ++u) {
      float w = W[(k4 + u) * 128 + t];
      acc[0] += xx0[u] * w; acc[1] += xx1[u] * w;
      acc[2] += xx2[u] * w; acc[3] += xx3[u] * w;
    }
  }
  #pragma unroll
  for (int rr = 0; rr < 4; ++rr) vout[(r0 + rr) * 128 + t] = silu_f(acc[rr]);
}

extern "C" void kernel_launch(void* const* d_in, const int* in_sizes, int n_in,
                              void* d_out, int out_size, void* d_ws, size_t ws_size,
                              hipStream_t stream) {
  const float* v_f    = (const float*)d_in[0];
  const float* e_f    = (const float*)d_in[1];
  const float* p_pe   = (const float*)d_in[2];
  const float* t_pe   = (const float*)d_in[3];
  const float* W_vpe  = (const float*)d_in[4];
  const float* b_vpe  = (const float*)d_in[5];
  const float* W_epe  = (const float*)d_in[6];
  const float* b_epe  = (const float*)d_in[7];
  const float* W_ev1  = (const float*)d_in[8];
  const float* b_ev1  = (const float*)d_in[9];
  const float* W_ev2  = (const float*)d_in[10];
  const float* b_ev2  = (const float*)d_in[11];
  const float* W_q    = (const float*)d_in[12];
  const float* b_q    = (const float*)d_in[13];
  const float* W_k    = (const float*)d_in[14];
  const float* b_k    = (const float*)d_in[15];
  const float* W_self = (const float*)d_in[16];
  const float* b_self = (const float*)d_in[17];
  const float* W_out  = (const float*)d_in[18];
  const float* b_out  = (const float*)d_in[19];

  char* ws = (char*)d_ws;
  unsigned short* vb16  = (unsigned short*)(ws + 0);        // 262144
  float*          qbuf  = (float*)(ws + 262144);            // 524288
  float*          kbuf  = (float*)(ws + 786432);            // 524288
  float*          sabuf = (float*)(ws + 1310720);           // 524288
  float*          vfbuf = (float*)(ws + 1835008);           // 524288
  float*          evic  = (float*)(ws + 2359296);           // 524288
  float*          pool  = (float*)(ws + 2883584);           // 4096
  float*          tc    = (float*)(ws + 2887680);           // 4096
  short*          wf1   = (short*)(ws + 2891776);           // 32768
  short*          wf2   = (short*)(ws + 2924544);           // 65536
  short*          wf3   = (short*)(ws + 2990080);           // 32768
  float*          pmax  = (float*)(ws + 3022848);           // 32768 -> 3.06MB

  float* v_out = (float*)d_out;
  float* out_e = (float*)d_out + 131072;

  k_prep<<<260, 256, 0, stream>>>(W_epe, wf1, W_ev1, wf2, W_ev2, wf3,
                                  t_pe, b_epe, tc);
  k_node<<<256, 128, 0, stream>>>(v_f, p_pe, t_pe, W_vpe, b_vpe, W_q, b_q,
                                  W_k, b_k, W_self, b_self, W_ev1, b_ev1,
                                  vb16, qbuf, kbuf, sabuf, evic);
  k_edge<<<1024, 256, 0, stream>>>(e_f, vb16, wf1, wf2, wf3, tc, evic,
                                   b_ev2, qbuf, kbuf, sabuf, out_e, vfbuf);
  k_pool1<<<64, 128, 0, stream>>>(vfbuf, pmax);
  k_pool2<<<8, 128, 0, stream>>>(pmax, pool);
  k_out<<<256, 128, 0, stream>>>(vfbuf, pool, W_out, b_out, v_out);
}

// Round 11
// 83.710 us; speedup vs baseline: 1.5733x; 1.5733x over previous
//
#include <hip/hip_runtime.h>
#include <hip/hip_bf16.h>

// GraphLayer: B=8, K=128, D=128, TPE=64, PPE=64, HEADS=8, G=16
// d_out = [v_out (8*128*128 f32) | e_value (8*16384*128 f32)]
//
// Round 11: k_edge / k_atten frozen at round-7 verbatim (best: 53.8us / pass).
// Tail restructured: k_front = prep+node merged (node split-K, 256thr),
// single k_pool, split-K k_out. 5 launches total.

typedef __attribute__((ext_vector_type(8)))  short bh8;   // 8 x bf16 (as short)
typedef __attribute__((ext_vector_type(16))) float f16v;  // MFMA 32x32 accum
typedef __attribute__((ext_vector_type(4)))  float f4v;

__device__ __forceinline__ unsigned short f2bf(float f) {
  unsigned u = __builtin_bit_cast(unsigned, f);
  u += 0x7fffu + ((u >> 16) & 1u);          // RNE
  return (unsigned short)(u >> 16);
}
__device__ __forceinline__ float silu_f(float x) {
  float e = __builtin_amdgcn_exp2f(x * -1.44269504088896f);   // e^-x
  return x * __builtin_amdgcn_rcpf(1.f + e);
}
__device__ __forceinline__ bh8 cvt8(f4v x, f4v y) {
  bh8 a;
  a[0] = (short)f2bf(x[0]); a[1] = (short)f2bf(x[1]);
  a[2] = (short)f2bf(x[2]); a[3] = (short)f2bf(x[3]);
  a[4] = (short)f2bf(y[0]); a[5] = (short)f2bf(y[1]);
  a[6] = (short)f2bf(y[2]); a[7] = (short)f2bf(y[3]);
  return a;
}
typedef const __attribute__((address_space(1))) unsigned int gq_t;
typedef __attribute__((address_space(3))) unsigned int lq_t;
__device__ __forceinline__ void gload_lds16(const void* g, void* l) {
  // dest is wave-uniform base; HW adds lane*16. src is per-lane.
  __builtin_amdgcn_global_load_lds((gq_t*)g, (lq_t*)l, 16, 0, 0);
}

// ---------- weight frag layout ----------
// frag idx = ((ni*ksteps + ks)*64 + lane)*8 + jj ; col n = ni*32+(l&31), k = ks*16+(l>>5)*8+jj
__device__ __forceinline__ void wfrag_work(const float* __restrict__ W,
                                           short* __restrict__ dst, int kdim,
                                           int blk, int nblk) {
  int ksteps = kdim >> 4;
  int total  = kdim * 128;
  for (int idx = blk * 256 + threadIdx.x; idx < total; idx += nblk * 256) {
    int jj = idx & 7;
    int l  = (idx >> 3) & 63;
    int rest = idx >> 9;
    int ks = rest % ksteps;
    int ni = rest / ksteps;
    int n  = ni * 32 + (l & 31);
    int kk = ks * 16 + ((l >> 5) << 3) + jj;
    dst[idx] = (short)f2bf(W[kk * 128 + n]);
  }
}

// ---------- k_front: prep (blocks 0-259) + node MLPs (blocks 260-515) ----------
__global__ __launch_bounds__(256) void k_front(
    const float* __restrict__ W_epe, short* __restrict__ wf1,
    const float* __restrict__ W_ev1, short* __restrict__ wf2,
    const float* __restrict__ W_ev2, short* __restrict__ wf3,
    const float* __restrict__ tpe, const float* __restrict__ bepe,
    float* __restrict__ tc,
    const float* __restrict__ vfeat, const float* __restrict__ ppe,
    const float* __restrict__ Wv, const float* __restrict__ bv,
    const float* __restrict__ Wq, const float* __restrict__ bq,
    const float* __restrict__ Wk, const float* __restrict__ bk,
    const float* __restrict__ Ws, const float* __restrict__ bs,
    const float* __restrict__ We, const float* __restrict__ be,
    unsigned short* __restrict__ vb16, float* __restrict__ q,
    float* __restrict__ kb, float* __restrict__ sa, float* __restrict__ evi) {
  const int blk = blockIdx.x;
  if (blk < 260) {
    if (blk < 64)       wfrag_work(W_epe, wf1, 128, blk, 64);
    else if (blk < 192) wfrag_work(W_ev1 + 128 * 128, wf2, 256, blk - 64, 128);
    else if (blk < 256) wfrag_work(W_ev2, wf3, 128, blk - 192, 64);
    else {
      int t = threadIdx.x;
      int b = (blk - 256) * 2 + (t >> 7);
      int n = t & 127;
      float a = bepe[n];
      for (int k2 = 0; k2 < 64; ++k2)
        a += tpe[b * 64 + k2] * W_epe[(128 + k2) * 128 + n];
      tc[b * 128 + n] = a;
    }
    return;
  }
  // ----- node: 4 rows/block, 256 threads (split work across wave-pairs)
  __shared__ float x[4][256];
  __shared__ float par[2][4][128];
  __shared__ float xv[4][128];
  const int r0 = (blk - 260) * 4;
  const int b  = r0 >> 7;
  const int t  = threadIdx.x;
  const int c  = t & 127;
  const int hf = t >> 7;               // wave-uniform (0 for waves 0-1, 1 for 2-3)
  #pragma unroll
  for (int rr = 0; rr < 4; ++rr) {
    int row = r0 + rr;
    x[rr][t] = (t < 128) ? vfeat[row * 128 + t]
             : (t < 192) ? ppe[row * 64 + (t - 128)]
                         : tpe[b * 64 + (t - 192)];
  }
  __syncthreads();
  // stage 1: v = silu(x@Wv + bv), K=256 split across hf
  {
    float a0 = 0.f, a1 = 0.f, a2 = 0.f, a3 = 0.f;
    const int k0 = hf * 128;
    for (int k4 = k0; k4 < k0 + 128; k4 += 4) {
      f4v x0 = *(const f4v*)&x[0][k4];
      f4v x1 = *(const f4v*)&x[1][k4];
      f4v x2 = *(const f4v*)&x[2][k4];
      f4v x3 = *(const f4v*)&x[3][k4];
      #pragma unroll
      for (int u = 0; u < 4; ++u) {
        float wv = Wv[(k4 + u) * 128 + c];
        a0 += x0[u] * wv; a1 += x1[u] * wv; a2 += x2[u] * wv; a3 += x3[u] * wv;
      }
    }
    par[hf][0][c] = a0; par[hf][1][c] = a1; par[hf][2][c] = a2; par[hf][3][c] = a3;
  }
  __syncthreads();
  if (hf == 0) {
    const float bvv = bv[c];
    #pragma unroll
    for (int rr = 0; rr < 4; ++rr) {
      float s = silu_f(par[0][rr][c] + par[1][rr][c] + bvv);
      vb16[(r0 + rr) * 128 + c] = f2bf(s);
      xv[rr][c] = s;
    }
  }
  __syncthreads();
  // stage 2: hf=0 -> q,k ; hf=1 -> self,evi   (K=128 each)
  const float* WA = hf ? Ws : Wq;
  const float* WB = hf ? We : Wk;
  const float  ba = hf ? bs[c] : bq[c];
  const float  bb = hf ? be[c] : bk[c];
  float aA[4] = {ba, ba, ba, ba}, aB[4] = {bb, bb, bb, bb};
  for (int k4 = 0; k4 < 128; k4 += 4) {
    f4v x0 = *(const f4v*)&xv[0][k4];
    f4v x1 = *(const f4v*)&xv[1][k4];
    f4v x2 = *(const f4v*)&xv[2][k4];
    f4v x3 = *(const f4v*)&xv[3][k4];
    #pragma unroll
    for (int u = 0; u < 4; ++u) {
      float wa = WA[(k4 + u) * 128 + c];
      float wb = WB[(k4 + u) * 128 + c];
      aA[0] += x0[u] * wa; aA[1] += x1[u] * wa; aA[2] += x2[u] * wa; aA[3] += x3[u] * wa;
      aB[0] += x0[u] * wb; aB[1] += x1[u] * wb; aB[2] += x2[u] * wb; aB[3] += x3[u] * wb;
    }
  }
  if (hf == 0) {
    #pragma unroll
    for (int rr = 0; rr < 4; ++rr) {
      q[(r0 + rr) * 128 + c]  = aA[rr];
      kb[(r0 + rr) * 128 + c] = aB[rr];
    }
  } else {
    #pragma unroll
    for (int rr = 0; rr < 4; ++rr) {
      sa[(r0 + rr) * 128 + c]  = silu_f(aA[rr]);
      evi[(r0 + rr) * 128 + c] = aB[rr];   // v_i@W_ev1[0:128] + b_ev1 (no silu)
    }
  }
}

// ---------- atten[b,i,j,g] = softmax_j( sum_h q*k / sqrt(24) ) ----------
__global__ void k_atten(const float* __restrict__ q, const float* __restrict__ kmat,
                        float* __restrict__ atten) {
  __shared__ float qr[128];
  __shared__ float s[128][17];
  __shared__ float red[8][17];
  __shared__ float gmax[16];
  __shared__ float gsum[16];
  const int bi = blockIdx.x;       // b*128+i
  const int b  = bi >> 7;
  const int t  = threadIdx.x;      // 128; acts as j
  qr[t] = q[bi * 128 + t];
  __syncthreads();
  const float sc = 0.20412414523193154f;  // 1/sqrt(24)
  float loc[16];
  const float* krow = kmat + (size_t)(b * 128 + t) * 128;
  #pragma unroll
  for (int g = 0; g < 16; ++g) {
    f4v k0 = *(const f4v*)&krow[g * 8];
    f4v k1 = *(const f4v*)&krow[g * 8 + 4];
    float a = 0.f;
    #pragma unroll
    for (int h = 0; h < 4; ++h) a += qr[g * 8 + h] * k0[h] + qr[g * 8 + 4 + h] * k1[h];
    loc[g] = a * sc;
    s[t][g] = loc[g];
  }
  __syncthreads();
  { int g = t & 15, c = t >> 4;
    float m = -1e30f;
    for (int j2 = c * 16; j2 < c * 16 + 16; ++j2) m = fmaxf(m, s[j2][g]);
    red[c][g] = m; }
  __syncthreads();
  if (t < 16) {
    float m = red[0][t];
    #pragma unroll
    for (int c = 1; c < 8; ++c) m = fmaxf(m, red[c][t]);
    gmax[t] = m;
  }
  __syncthreads();
  #pragma unroll
  for (int g = 0; g < 16; ++g) {
    loc[g] = __builtin_amdgcn_exp2f((loc[g] - gmax[g]) * 1.44269504088896f);
    s[t][g] = loc[g];
  }
  __syncthreads();
  { int g = t & 15, c = t >> 4;
    float m = 0.f;
    for (int j2 = c * 16; j2 < c * 16 + 16; ++j2) m += s[j2][g];
    red[c][g] = m; }
  __syncthreads();
  if (t < 16) {
    float m = 0.f;
    #pragma unroll
    for (int c = 0; c < 8; ++c) m += red[c][t];
    gsum[t] = m;
  }
  __syncthreads();
  float* ab = atten + (size_t)bi * 2048 + (size_t)t * 16;
  #pragma unroll
  for (int g = 0; g < 16; ++g) ab[g] = loc[g] * __builtin_amdgcn_rcpf(gsum[g]);
}

// ---------- fused edge chain + in-block aggregation (round-7 verbatim) ----------
__global__ __launch_bounds__(256) void k_edge(
    const float* __restrict__ ef, const unsigned short* __restrict__ vb,
    const short* __restrict__ wf1, const short* __restrict__ wf2,
    const short* __restrict__ wf3, const float* __restrict__ tc,
    const float* __restrict__ evic, const float* __restrict__ bev2,
    const float* __restrict__ atten, const float* __restrict__ sab,
    float* __restrict__ oute, float* __restrict__ vfb) {
  __shared__ __align__(16) unsigned short wbuf0[4096];      // 8KB chunk buffer
  __shared__ __align__(16) unsigned short wbuf1[4096];      // 8KB chunk buffer
  __shared__ __align__(16) unsigned short hbuf[128 * 136];  // 34816B, 272B stride
  const int bi  = blockIdx.x;
  const int b   = bi >> 7;
  const int tid = threadIdx.x;
  const int w   = tid >> 6;
  const int l   = tid & 63;
  const int row = w * 32 + (l & 31);          // j index (A rows)
  const int kh  = (l >> 5) << 3;              // 0 or 8
  const int cb  = l & 31;                     // C/D col base
  const int rb  = w * 32 + ((l >> 5) << 2);   // C/D row base

  const float* efr = ef + (size_t)(bi * 128 + row) * 128;
  const unsigned short* vj = vb + (size_t)(b * 128 + row) * 128;

  auto stage2 = [&](const short* wfp, int KST, int kc, unsigned short* dstb) {
    #pragma unroll
    for (int it = 0; it < 2; ++it) {
      int g  = it * 4 + w;            // slot g: ni=g&3(=w), kso=g>>2(=it)
      int ni = g & 3, kso = g >> 2;
      const short* src = wfp + ((size_t)(ni * KST + kc * 2 + kso) * 64 + l) * 8;
      gload_lds16(src, dstb + g * 512);
    }
  };
  f16v acc[4];
  auto compute2 = [&](const unsigned short* ws2, bh8 aa, bh8 ab2) {
    #pragma unroll
    for (int ni = 0; ni < 4; ++ni) {
      bh8 b0 = *(const bh8*)&ws2[ni * 512 + l * 8];
      acc[ni] = __builtin_amdgcn_mfma_f32_32x32x16_bf16(aa, b0, acc[ni], 0, 0, 0);
    }
    #pragma unroll
    for (int ni = 0; ni < 4; ++ni) {
      bh8 b1 = *(const bh8*)&ws2[(4 + ni) * 512 + l * 8];
      acc[ni] = __builtin_amdgcn_mfma_f32_32x32x16_bf16(ab2, b1, acc[ni], 0, 0, 0);
    }
  };
  auto ldA = [&](int t) -> bh8 {
    if (t < 8) {
      const float* p = efr + t * 16 + kh;
      f4v x0 = *(const f4v*)p;
      f4v x1 = *(const f4v*)(p + 4);
      return cvt8(x0, x1);
    } else if (t < 16) {
      return *(const bh8*)(vj + (t - 8) * 16 + kh);
    } else if (t < 24) {
      return *(const bh8*)&hbuf[row * 136 + (t - 16) * 16 + kh];
    } else {
      return *(const bh8*)&hbuf[row * 136 + (t - 24) * 16 + kh];
    }
  };

  float tin[4], ein[4];
  #pragma unroll
  for (int ni = 0; ni < 4; ++ni) {
    tin[ni] = tc[b * 128 + ni * 32 + cb];
    ein[ni] = evic[bi * 128 + ni * 32 + cb];
  }
  #pragma unroll
  for (int ni = 0; ni < 4; ++ni)
    #pragma unroll
    for (int r = 0; r < 16; ++r) acc[ni][r] = tin[ni];

  stage2(wf1, 8, 0, wbuf0);
  bh8 a0c = ldA(0), a1c = ldA(1);
  __syncthreads();

  #pragma unroll
  for (int c = 0; c < 16; ++c) {
    if (c + 1 < 16) {
      const short* wp; int KST, kc;
      if (c + 1 < 4)       { wp = wf1; KST = 8;  kc = c + 1; }
      else if (c + 1 < 12) { wp = wf2; KST = 16; kc = c + 1 - 4; }
      else                 { wp = wf3; KST = 8;  kc = c + 1 - 12; }
      stage2(wp, KST, kc, (c & 1) ? wbuf0 : wbuf1);
    }
    bh8 a0n, a1n;
    const bool pre = (c + 1 < 16) && (c != 11);   // c=11->12 crosses h2 epi
    if (pre) { a0n = ldA(2 * (c + 1)); a1n = ldA(2 * (c + 1) + 1); }
    compute2((c & 1) ? wbuf1 : wbuf0, a0c, a1c);
    if (c == 3) {            // h1 -> hbuf (same-wave rows); acc := evic
      #pragma unroll
      for (int ni = 0; ni < 4; ++ni) {
        int n = ni * 32 + cb;
        #pragma unroll
        for (int r = 0; r < 16; ++r) {
          int rj = rb + (r & 3) + ((r >> 2) << 3);
          hbuf[rj * 136 + n] = f2bf(silu_f(acc[ni][r]));
          acc[ni][r] = ein[ni];
        }
      }
    }
    if (c == 11) {           // h2 -> hbuf; acc := 0; L3 A direct from hbuf
      #pragma unroll
      for (int ni = 0; ni < 4; ++ni) {
        int n = ni * 32 + cb;
        #pragma unroll
        for (int r = 0; r < 16; ++r) {
          int rj = rb + (r & 3) + ((r >> 2) << 3);
          hbuf[rj * 136 + n] = f2bf(silu_f(acc[ni][r]));
          acc[ni][r] = 0.f;
        }
      }
      a0c = ldA(24); a1c = ldA(25);
    } else if (pre) {
      a0c = a0n; a1c = a1n;
    }
    __syncthreads();
  }

  // ===== epilogue: bias + e_value store
  #pragma unroll
  for (int ni = 0; ni < 4; ++ni) {
    int n = ni * 32 + cb;
    float bv = bev2[n];
    #pragma unroll
    for (int r = 0; r < 16; ++r) {
      int rj = rb + (r & 3) + ((r >> 2) << 3);
      acc[ni][r] += bv;
      oute[(size_t)(bi * 128 + rj) * 128 + n] = acc[ni][r];
    }
  }

  // ===== in-block aggregation: vf[n] = sum_j atten[j][n>>3]*ev[j][n] + silu_self
  __syncthreads();                       // all h2 hbuf reads done before overwrite
  float* attf = (float*)hbuf;            // [j][gl][ni] transposed, 2048 f32
  float* aggl = attf + 2048;             // [4 waves][128]
  const float* ap = atten + (size_t)bi * 2048;
  #pragma unroll
  for (int u = 0; u < 8; ++u) {
    int idx = u * 256 + tid;
    float v = ap[idx];
    int j2 = idx >> 4, g = idx & 15;
    attf[j2 * 16 + (g & 3) * 4 + (g >> 2)] = v;
  }
  float sav = 0.f;
  if (tid < 128) sav = sab[(size_t)bi * 128 + tid];
  __syncthreads();
  float p0 = 0.f, p1 = 0.f, p2 = 0.f, p3 = 0.f;
  const int gl = (l & 31) >> 3;
  #pragma unroll
  for (int r = 0; r < 16; ++r) {
    int rj = rb + (r & 3) + ((r >> 2) << 3);
    f4v av = *(const f4v*)&attf[rj * 16 + gl * 4];
    p0 += av[0] * acc[0][r]; p1 += av[1] * acc[1][r];
    p2 += av[2] * acc[2][r]; p3 += av[3] * acc[3][r];
  }
  p0 += __shfl_xor(p0, 32); p1 += __shfl_xor(p1, 32);
  p2 += __shfl_xor(p2, 32); p3 += __shfl_xor(p3, 32);
  if (l < 32) {
    aggl[w * 128 +  0 + l] = p0;
    aggl[w * 128 + 32 + l] = p1;
    aggl[w * 128 + 64 + l] = p2;
    aggl[w * 128 + 96 + l] = p3;
  }
  __syncthreads();
  if (tid < 128) {
    vfb[(size_t)bi * 128 + tid] =
        aggl[tid] + aggl[128 + tid] + aggl[256 + tid] + aggl[384 + tid] + sav;
  }
}

// ---------- max-pool over i (single kernel) ----------
__global__ void k_pool(const float* __restrict__ vfb, float* __restrict__ pool) {
  const int b = blockIdx.x, t = threadIdx.x;
  float m0 = -1e30f, m1 = -1e30f, m2 = -1e30f, m3 = -1e30f;
  for (int i = 0; i < 128; i += 4) {
    m0 = fmaxf(m0, vfb[(size_t)(b * 128 + i + 0) * 128 + t]);
    m1 = fmaxf(m1, vfb[(size_t)(b * 128 + i + 1) * 128 + t]);
    m2 = fmaxf(m2, vfb[(size_t)(b * 128 + i + 2) * 128 + t]);
    m3 = fmaxf(m3, vfb[(size_t)(b * 128 + i + 3) * 128 + t]);
  }
  pool[b * 128 + t] = fmaxf(fmaxf(m0, m1), fmaxf(m2, m3));
}

// ---------- out MLP: v_out = silu([vf|pool] @ W_out + b), split-K ----------
__global__ __launch_bounds__(256) void k_out(
    const float* __restrict__ vfb, const float* __restrict__ pool,
    const float* __restrict__ W, const float* __restrict__ bias,
    float* __restrict__ vout) {
  __shared__ float x[4][256];
  __shared__ float par[2][4][128];
  const int r0 = blockIdx.x * 4;
  const int b  = r0 >> 7;
  const int t  = threadIdx.x;
  const int c  = t & 127;
  const int hf = t >> 7;
  #pragma unroll
  for (int rr = 0; rr < 4; ++rr)
    x[rr][t] = (t < 128) ? vfb[(r0 + rr) * 128 + t] : pool[b * 128 + (t - 128)];
  __syncthreads();
  {
    float a0 = 0.f, a1 = 0.f, a2 = 0.f, a3 = 0.f;
    const int k0 = hf * 128;
    for (int k4 = k0; k4 < k0 + 128; k4 += 4) {
      f4v x0 = *(const f4v*)&x[0][k4];
      f4v x1 = *(const f4v*)&x[1][k4];
      f4v x2 = *(const f4v*)&x[2][k4];
      f4v x3 = *(const f4v*)&x[3][k4];
      #pragma unroll
      for (int u = 0; u < 4; ++u) {
        float wv = W[(k4 + u) * 128 + c];
        a0 += x0[u] * wv; a1 += x1[u] * wv; a2 += x2[u] * wv; a3 += x3[u] * wv;
      }
    }
    par[hf][0][c] = a0; par[hf][1][c] = a1; par[hf][2][c] = a2; par[hf][3][c] = a3;
  }
  __syncthreads();
  if (hf == 0) {
    const float bvv = bias[c];
    #pragma unroll
    for (int rr = 0; rr < 4; ++rr)
      vout[(r0 + rr) * 128 + c] = silu_f(par[0][rr][c] + par[1][rr][c] + bvv);
  }
}

extern "C" void kernel_launch(void* const* d_in, const int* in_sizes, int n_in,
                              void* d_out, int out_size, void* d_ws, size_t ws_size,
                              hipStream_t stream) {
  const float* v_f    = (const float*)d_in[0];
  const float* e_f    = (const float*)d_in[1];
  const float* p_pe   = (const float*)d_in[2];
  const float* t_pe   = (const float*)d_in[3];
  const float* W_vpe  = (const float*)d_in[4];
  const float* b_vpe  = (const float*)d_in[5];
  const float* W_epe  = (const float*)d_in[6];
  const float* b_epe  = (const float*)d_in[7];
  const float* W_ev1  = (const float*)d_in[8];
  const float* b_ev1  = (const float*)d_in[9];
  const float* W_ev2  = (const float*)d_in[10];
  const float* b_ev2  = (const float*)d_in[11];
  const float* W_q    = (const float*)d_in[12];
  const float* b_q    = (const float*)d_in[13];
  const float* W_k    = (const float*)d_in[14];
  const float* b_k    = (const float*)d_in[15];
  const float* W_self = (const float*)d_in[16];
  const float* b_self = (const float*)d_in[17];
  const float* W_out  = (const float*)d_in[18];
  const float* b_out  = (const float*)d_in[19];

  char* ws = (char*)d_ws;
  unsigned short* vb16  = (unsigned short*)(ws + 0);        // 262144
  float*          qbuf  = (float*)(ws + 262144);            // 524288
  float*          kbuf  = (float*)(ws + 786432);            // 524288
  float*          sabuf = (float*)(ws + 1310720);           // 524288
  float*          vfbuf = (float*)(ws + 1835008);           // 524288
  float*          evic  = (float*)(ws + 2359296);           // 524288
  float*          pool  = (float*)(ws + 2883584);           // 4096
  float*          tc    = (float*)(ws + 2887680);           // 4096
  short*          wf1   = (short*)(ws + 2891776);           // 32768
  short*          wf2   = (short*)(ws + 2924544);           // 65536
  short*          wf3   = (short*)(ws + 2990080);           // 32768
  float*          atten = (float*)(ws + 3022848);           // 8388608 -> 11.4MB

  float* v_out = (float*)d_out;
  float* out_e = (float*)d_out + 131072;

  k_front<<<516, 256, 0, stream>>>(W_epe, wf1, W_ev1, wf2, W_ev2, wf3,
                                   t_pe, b_epe, tc,
                                   v_f, p_pe, W_vpe, b_vpe, W_q, b_q,
                                   W_k, b_k, W_self, b_self, W_ev1, b_ev1,
                                   vb16, qbuf, kbuf, sabuf, evic);
  k_atten<<<1024, 128, 0, stream>>>(qbuf, kbuf, atten);
  k_edge<<<1024, 256, 0, stream>>>(e_f, vb16, wf1, wf2, wf3, tc, evic,
                                   b_ev2, atten, sabuf, out_e, vfbuf);
  k_pool<<<8, 128, 0, stream>>>(vfbuf, pool);
  k_out<<<256, 256, 0, stream>>>(vfbuf, pool, W_out, b_out, v_out);
}

// Round 12
// 81.686 us; speedup vs baseline: 1.6123x; 1.0248x over previous
//
#include <hip/hip_runtime.h>
#include <hip/hip_bf16.h>

// GraphLayer: B=8, K=128, D=128, TPE=64, PPE=64, HEADS=8, G=16
// d_out = [v_out (8*128*128 f32) | e_value (8*16384*128 f32)]
//
// Round 12: round-11 structure (83.7us) + (1) XCD-swizzled k_edge blockIdx,
// (2) k_pool replaced by monotonic-uint atomicMax in k_edge tail (poolU
// zero-init in k_front), (3) k_atten batches 2 i's per 256-thread block.
// 4 launches: front -> atten -> edge -> out.

typedef __attribute__((ext_vector_type(8)))  short bh8;   // 8 x bf16 (as short)
typedef __attribute__((ext_vector_type(16))) float f16v;  // MFMA 32x32 accum
typedef __attribute__((ext_vector_type(4)))  float f4v;

__device__ __forceinline__ unsigned short f2bf(float f) {
  unsigned u = __builtin_bit_cast(unsigned, f);
  u += 0x7fffu + ((u >> 16) & 1u);          // RNE
  return (unsigned short)(u >> 16);
}
__device__ __forceinline__ float silu_f(float x) {
  float e = __builtin_amdgcn_exp2f(x * -1.44269504088896f);   // e^-x
  return x * __builtin_amdgcn_rcpf(1.f + e);
}
__device__ __forceinline__ bh8 cvt8(f4v x, f4v y) {
  bh8 a;
  a[0] = (short)f2bf(x[0]); a[1] = (short)f2bf(x[1]);
  a[2] = (short)f2bf(x[2]); a[3] = (short)f2bf(x[3]);
  a[4] = (short)f2bf(y[0]); a[5] = (short)f2bf(y[1]);
  a[6] = (short)f2bf(y[2]); a[7] = (short)f2bf(y[3]);
  return a;
}
typedef const __attribute__((address_space(1))) unsigned int gq_t;
typedef __attribute__((address_space(3))) unsigned int lq_t;
__device__ __forceinline__ void gload_lds16(const void* g, void* l) {
  // dest is wave-uniform base; HW adds lane*16. src is per-lane.
  __builtin_amdgcn_global_load_lds((gq_t*)g, (lq_t*)l, 16, 0, 0);
}
// monotonic f32 <-> u32 mapping for atomicMax-based float max
__device__ __forceinline__ unsigned fkey(float x) {
  unsigned u = __builtin_bit_cast(unsigned, x);
  return u ^ (((unsigned)((int)u >> 31)) | 0x80000000u);
}
__device__ __forceinline__ float funkey(unsigned key) {
  unsigned u = (key & 0x80000000u) ? (key ^ 0x80000000u) : ~key;
  return __builtin_bit_cast(float, u);
}

// ---------- weight frag layout ----------
// frag idx = ((ni*ksteps + ks)*64 + lane)*8 + jj ; col n = ni*32+(l&31), k = ks*16+(l>>5)*8+jj
__device__ __forceinline__ void wfrag_work(const float* __restrict__ W,
                                           short* __restrict__ dst, int kdim,
                                           int blk, int nblk) {
  int ksteps = kdim >> 4;
  int total  = kdim * 128;
  for (int idx = blk * 256 + threadIdx.x; idx < total; idx += nblk * 256) {
    int jj = idx & 7;
    int l  = (idx >> 3) & 63;
    int rest = idx >> 9;
    int ks = rest % ksteps;
    int ni = rest / ksteps;
    int n  = ni * 32 + (l & 31);
    int kk = ks * 16 + ((l >> 5) << 3) + jj;
    dst[idx] = (short)f2bf(W[kk * 128 + n]);
  }
}

// ---------- k_front: prep (0-259) + poolU zero (516) + node MLPs (260-515) ----------
__global__ __launch_bounds__(256) void k_front(
    const float* __restrict__ W_epe, short* __restrict__ wf1,
    const float* __restrict__ W_ev1, short* __restrict__ wf2,
    const float* __restrict__ W_ev2, short* __restrict__ wf3,
    const float* __restrict__ tpe, const float* __restrict__ bepe,
    float* __restrict__ tc, unsigned* __restrict__ poolU,
    const float* __restrict__ vfeat, const float* __restrict__ ppe,
    const float* __restrict__ Wv, const float* __restrict__ bv,
    const float* __restrict__ Wq, const float* __restrict__ bq,
    const float* __restrict__ Wk, const float* __restrict__ bk,
    const float* __restrict__ Ws, const float* __restrict__ bs,
    const float* __restrict__ We, const float* __restrict__ be,
    unsigned short* __restrict__ vb16, float* __restrict__ q,
    float* __restrict__ kb, float* __restrict__ sa, float* __restrict__ evi) {
  const int blk = blockIdx.x;
  if (blk < 260) {
    if (blk < 64)       wfrag_work(W_epe, wf1, 128, blk, 64);
    else if (blk < 192) wfrag_work(W_ev1 + 128 * 128, wf2, 256, blk - 64, 128);
    else if (blk < 256) wfrag_work(W_ev2, wf3, 128, blk - 192, 64);
    else {
      int t = threadIdx.x;
      int b = (blk - 256) * 2 + (t >> 7);
      int n = t & 127;
      float a = bepe[n];
      for (int k2 = 0; k2 < 64; ++k2)
        a += tpe[b * 64 + k2] * W_epe[(128 + k2) * 128 + n];
      tc[b * 128 + n] = a;
    }
    return;
  }
  if (blk >= 516) {                       // zero poolU each call (re-used buffer)
    for (int j = threadIdx.x; j < 1024; j += 256) poolU[j] = 0u;
    return;
  }
  // ----- node: 4 rows/block, 256 threads (split work across wave-pairs)
  __shared__ float x[4][256];
  __shared__ float par[2][4][128];
  __shared__ float xv[4][128];
  const int r0 = (blk - 260) * 4;
  const int b  = r0 >> 7;
  const int t  = threadIdx.x;
  const int c  = t & 127;
  const int hf = t >> 7;               // wave-uniform (0 for waves 0-1, 1 for 2-3)
  #pragma unroll
  for (int rr = 0; rr < 4; ++rr) {
    int row = r0 + rr;
    x[rr][t] = (t < 128) ? vfeat[row * 128 + t]
             : (t < 192) ? ppe[row * 64 + (t - 128)]
                         : tpe[b * 64 + (t - 192)];
  }
  __syncthreads();
  // stage 1: v = silu(x@Wv + bv), K=256 split across hf
  {
    float a0 = 0.f, a1 = 0.f, a2 = 0.f, a3 = 0.f;
    const int k0 = hf * 128;
    for (int k4 = k0; k4 < k0 + 128; k4 += 4) {
      f4v x0 = *(const f4v*)&x[0][k4];
      f4v x1 = *(const f4v*)&x[1][k4];
      f4v x2 = *(const f4v*)&x[2][k4];
      f4v x3 = *(const f4v*)&x[3][k4];
      #pragma unroll
      for (int u = 0; u < 4; ++u) {
        float wv = Wv[(k4 + u) * 128 + c];
        a0 += x0[u] * wv; a1 += x1[u] * wv; a2 += x2[u] * wv; a3 += x3[u] * wv;
      }
    }
    par[hf][0][c] = a0; par[hf][1][c] = a1; par[hf][2][c] = a2; par[hf][3][c] = a3;
  }
  __syncthreads();
  if (hf == 0) {
    const float bvv = bv[c];
    #pragma unroll
    for (int rr = 0; rr < 4; ++rr) {
      float s = silu_f(par[0][rr][c] + par[1][rr][c] + bvv);
      vb16[(r0 + rr) * 128 + c] = f2bf(s);
      xv[rr][c] = s;
    }
  }
  __syncthreads();
  // stage 2: hf=0 -> q,k ; hf=1 -> self,evi   (K=128 each)
  const float* WA = hf ? Ws : Wq;
  const float* WB = hf ? We : Wk;
  const float  ba = hf ? bs[c] : bq[c];
  const float  bb = hf ? be[c] : bk[c];
  float aA[4] = {ba, ba, ba, ba}, aB[4] = {bb, bb, bb, bb};
  for (int k4 = 0; k4 < 128; k4 += 4) {
    f4v x0 = *(const f4v*)&xv[0][k4];
    f4v x1 = *(const f4v*)&xv[1][k4];
    f4v x2 = *(const f4v*)&xv[2][k4];
    f4v x3 = *(const f4v*)&xv[3][k4];
    #pragma unroll
    for (int u = 0; u < 4; ++u) {
      float wa = WA[(k4 + u) * 128 + c];
      float wb = WB[(k4 + u) * 128 + c];
      aA[0] += x0[u] * wa; aA[1] += x1[u] * wa; aA[2] += x2[u] * wa; aA[3] += x3[u] * wa;
      aB[0] += x0[u] * wb; aB[1] += x1[u] * wb; aB[2] += x2[u] * wb; aB[3] += x3[u] * wb;
    }
  }
  if (hf == 0) {
    #pragma unroll
    for (int rr = 0; rr < 4; ++rr) {
      q[(r0 + rr) * 128 + c]  = aA[rr];
      kb[(r0 + rr) * 128 + c] = aB[rr];
    }
  } else {
    #pragma unroll
    for (int rr = 0; rr < 4; ++rr) {
      sa[(r0 + rr) * 128 + c]  = silu_f(aA[rr]);
      evi[(r0 + rr) * 128 + c] = aB[rr];   // v_i@W_ev1[0:128] + b_ev1 (no silu)
    }
  }
}

// ---------- atten: 2 i's per 256-thread block (512 blocks) ----------
__global__ __launch_bounds__(256) void k_atten(
    const float* __restrict__ q, const float* __restrict__ kmat,
    float* __restrict__ atten) {
  __shared__ float qr[2][128];
  __shared__ float s[2][128][17];
  __shared__ float red[2][8][17];
  __shared__ float gmax[2][16];
  __shared__ float gsum[2][16];
  const int tid = threadIdx.x;
  const int hi  = tid >> 7;              // which i of the pair
  const int tt  = tid & 127;             // acts as j
  const int bi  = blockIdx.x * 2 + hi;   // same b for both halves (bi0 even)
  const int b   = bi >> 7;
  qr[hi][tt] = q[(size_t)bi * 128 + tt];
  __syncthreads();
  const float sc = 0.20412414523193154f; // 1/sqrt(24)
  float loc[16];
  const float* krow = kmat + (size_t)(b * 128 + tt) * 128;
  #pragma unroll
  for (int g = 0; g < 16; ++g) {
    f4v k0 = *(const f4v*)&krow[g * 8];
    f4v k1 = *(const f4v*)&krow[g * 8 + 4];
    float a = 0.f;
    #pragma unroll
    for (int h = 0; h < 4; ++h)
      a += qr[hi][g * 8 + h] * k0[h] + qr[hi][g * 8 + 4 + h] * k1[h];
    loc[g] = a * sc;
    s[hi][tt][g] = loc[g];
  }
  __syncthreads();
  { int g = tt & 15, c = tt >> 4;
    float m = -1e30f;
    for (int j2 = c * 16; j2 < c * 16 + 16; ++j2) m = fmaxf(m, s[hi][j2][g]);
    red[hi][c][g] = m; }
  __syncthreads();
  if (tt < 16) {
    float m = red[hi][0][tt];
    #pragma unroll
    for (int c = 1; c < 8; ++c) m = fmaxf(m, red[hi][c][tt]);
    gmax[hi][tt] = m;
  }
  __syncthreads();
  #pragma unroll
  for (int g = 0; g < 16; ++g) {
    loc[g] = __builtin_amdgcn_exp2f((loc[g] - gmax[hi][g]) * 1.44269504088896f);
    s[hi][tt][g] = loc[g];
  }
  __syncthreads();
  { int g = tt & 15, c = tt >> 4;
    float m = 0.f;
    for (int j2 = c * 16; j2 < c * 16 + 16; ++j2) m += s[hi][j2][g];
    red[hi][c][g] = m; }
  __syncthreads();
  if (tt < 16) {
    float m = 0.f;
    #pragma unroll
    for (int c = 0; c < 8; ++c) m += red[hi][c][tt];
    gsum[hi][tt] = m;
  }
  __syncthreads();
  float* ab = atten + (size_t)bi * 2048 + (size_t)tt * 16;
  #pragma unroll
  for (int g = 0; g < 16; ++g) ab[g] = loc[g] * __builtin_amdgcn_rcpf(gsum[hi][g]);
}

// ---------- fused edge chain + in-block aggregation (round-7 loop, XCD swizzle) ----------
__global__ __launch_bounds__(256) void k_edge(
    const float* __restrict__ ef, const unsigned short* __restrict__ vb,
    const short* __restrict__ wf1, const short* __restrict__ wf2,
    const short* __restrict__ wf3, const float* __restrict__ tc,
    const float* __restrict__ evic, const float* __restrict__ bev2,
    const float* __restrict__ atten, const float* __restrict__ sab,
    float* __restrict__ oute, float* __restrict__ vfb,
    unsigned* __restrict__ poolU) {
  __shared__ __align__(16) unsigned short wbuf0[4096];      // 8KB chunk buffer
  __shared__ __align__(16) unsigned short wbuf1[4096];      // 8KB chunk buffer
  __shared__ __align__(16) unsigned short hbuf[128 * 136];  // 34816B, 272B stride
  // XCD-aware bijective swizzle (1024 % 8 == 0): XCD x gets bi in [x*128,(x+1)*128)
  const int bi  = ((blockIdx.x & 7) << 7) | (blockIdx.x >> 3);
  const int b   = bi >> 7;
  const int tid = threadIdx.x;
  const int w   = tid >> 6;
  const int l   = tid & 63;
  const int row = w * 32 + (l & 31);          // j index (A rows)
  const int kh  = (l >> 5) << 3;              // 0 or 8
  const int cb  = l & 31;                     // C/D col base
  const int rb  = w * 32 + ((l >> 5) << 2);   // C/D row base

  const float* efr = ef + (size_t)(bi * 128 + row) * 128;
  const unsigned short* vj = vb + (size_t)(b * 128 + row) * 128;

  auto stage2 = [&](const short* wfp, int KST, int kc, unsigned short* dstb) {
    #pragma unroll
    for (int it = 0; it < 2; ++it) {
      int g  = it * 4 + w;            // slot g: ni=g&3(=w), kso=g>>2(=it)
      int ni = g & 3, kso = g >> 2;
      const short* src = wfp + ((size_t)(ni * KST + kc * 2 + kso) * 64 + l) * 8;
      gload_lds16(src, dstb + g * 512);
    }
  };
  f16v acc[4];
  auto compute2 = [&](const unsigned short* ws2, bh8 aa, bh8 ab2) {
    #pragma unroll
    for (int ni = 0; ni < 4; ++ni) {
      bh8 b0 = *(const bh8*)&ws2[ni * 512 + l * 8];
      acc[ni] = __builtin_amdgcn_mfma_f32_32x32x16_bf16(aa, b0, acc[ni], 0, 0, 0);
    }
    #pragma unroll
    for (int ni = 0; ni < 4; ++ni) {
      bh8 b1 = *(const bh8*)&ws2[(4 + ni) * 512 + l * 8];
      acc[ni] = __builtin_amdgcn_mfma_f32_32x32x16_bf16(ab2, b1, acc[ni], 0, 0, 0);
    }
  };
  auto ldA = [&](int t) -> bh8 {
    if (t < 8) {
      const float* p = efr + t * 16 + kh;
      f4v x0 = *(const f4v*)p;
      f4v x1 = *(const f4v*)(p + 4);
      return cvt8(x0, x1);
    } else if (t < 16) {
      return *(const bh8*)(vj + (t - 8) * 16 + kh);
    } else if (t < 24) {
      return *(const bh8*)&hbuf[row * 136 + (t - 16) * 16 + kh];
    } else {
      return *(const bh8*)&hbuf[row * 136 + (t - 24) * 16 + kh];
    }
  };

  float tin[4], ein[4];
  #pragma unroll
  for (int ni = 0; ni < 4; ++ni) {
    tin[ni] = tc[b * 128 + ni * 32 + cb];
    ein[ni] = evic[bi * 128 + ni * 32 + cb];
  }
  #pragma unroll
  for (int ni = 0; ni < 4; ++ni)
    #pragma unroll
    for (int r = 0; r < 16; ++r) acc[ni][r] = tin[ni];

  stage2(wf1, 8, 0, wbuf0);
  bh8 a0c = ldA(0), a1c = ldA(1);
  __syncthreads();

  #pragma unroll
  for (int c = 0; c < 16; ++c) {
    if (c + 1 < 16) {
      const short* wp; int KST, kc;
      if (c + 1 < 4)       { wp = wf1; KST = 8;  kc = c + 1; }
      else if (c + 1 < 12) { wp = wf2; KST = 16; kc = c + 1 - 4; }
      else                 { wp = wf3; KST = 8;  kc = c + 1 - 12; }
      stage2(wp, KST, kc, (c & 1) ? wbuf0 : wbuf1);
    }
    bh8 a0n, a1n;
    const bool pre = (c + 1 < 16) && (c != 11);   // c=11->12 crosses h2 epi
    if (pre) { a0n = ldA(2 * (c + 1)); a1n = ldA(2 * (c + 1) + 1); }
    compute2((c & 1) ? wbuf1 : wbuf0, a0c, a1c);
    if (c == 3) {            // h1 -> hbuf (same-wave rows); acc := evic
      #pragma unroll
      for (int ni = 0; ni < 4; ++ni) {
        int n = ni * 32 + cb;
        #pragma unroll
        for (int r = 0; r < 16; ++r) {
          int rj = rb + (r & 3) + ((r >> 2) << 3);
          hbuf[rj * 136 + n] = f2bf(silu_f(acc[ni][r]));
          acc[ni][r] = ein[ni];
        }
      }
    }
    if (c == 11) {           // h2 -> hbuf; acc := 0; L3 A direct from hbuf
      #pragma unroll
      for (int ni = 0; ni < 4; ++ni) {
        int n = ni * 32 + cb;
        #pragma unroll
        for (int r = 0; r < 16; ++r) {
          int rj = rb + (r & 3) + ((r >> 2) << 3);
          hbuf[rj * 136 + n] = f2bf(silu_f(acc[ni][r]));
          acc[ni][r] = 0.f;
        }
      }
      a0c = ldA(24); a1c = ldA(25);
    } else if (pre) {
      a0c = a0n; a1c = a1n;
    }
    __syncthreads();
  }

  // ===== epilogue: bias + e_value store
  #pragma unroll
  for (int ni = 0; ni < 4; ++ni) {
    int n = ni * 32 + cb;
    float bv = bev2[n];
    #pragma unroll
    for (int r = 0; r < 16; ++r) {
      int rj = rb + (r & 3) + ((r >> 2) << 3);
      acc[ni][r] += bv;
      oute[(size_t)(bi * 128 + rj) * 128 + n] = acc[ni][r];
    }
  }

  // ===== in-block aggregation: vf[n] = sum_j atten[j][n>>3]*ev[j][n] + silu_self
  __syncthreads();                       // all h2 hbuf reads done before overwrite
  float* attf = (float*)hbuf;            // [j][gl][ni] transposed, 2048 f32
  float* aggl = attf + 2048;             // [4 waves][128]
  const float* ap = atten + (size_t)bi * 2048;
  #pragma unroll
  for (int u = 0; u < 8; ++u) {
    int idx = u * 256 + tid;
    float v = ap[idx];
    int j2 = idx >> 4, g = idx & 15;
    attf[j2 * 16 + (g & 3) * 4 + (g >> 2)] = v;
  }
  float sav = 0.f;
  if (tid < 128) sav = sab[(size_t)bi * 128 + tid];
  __syncthreads();
  float p0 = 0.f, p1 = 0.f, p2 = 0.f, p3 = 0.f;
  const int gl = (l & 31) >> 3;
  #pragma unroll
  for (int r = 0; r < 16; ++r) {
    int rj = rb + (r & 3) + ((r >> 2) << 3);
    f4v av = *(const f4v*)&attf[rj * 16 + gl * 4];
    p0 += av[0] * acc[0][r]; p1 += av[1] * acc[1][r];
    p2 += av[2] * acc[2][r]; p3 += av[3] * acc[3][r];
  }
  p0 += __shfl_xor(p0, 32); p1 += __shfl_xor(p1, 32);
  p2 += __shfl_xor(p2, 32); p3 += __shfl_xor(p3, 32);
  if (l < 32) {
    aggl[w * 128 +  0 + l] = p0;
    aggl[w * 128 + 32 + l] = p1;
    aggl[w * 128 + 64 + l] = p2;
    aggl[w * 128 + 96 + l] = p3;
  }
  __syncthreads();
  if (tid < 128) {
    float vf = aggl[tid] + aggl[128 + tid] + aggl[256 + tid] + aggl[384 + tid] + sav;
    vfb[(size_t)bi * 128 + tid] = vf;
    atomicMax(&poolU[b * 128 + tid], fkey(vf));   // device-scope, XCD-coherent
  }
}

// ---------- out MLP: v_out = silu([vf|pool] @ W_out + b), split-K ----------
__global__ __launch_bounds__(256) void k_out(
    const float* __restrict__ vfb, const unsigned* __restrict__ poolU,
    const float* __restrict__ W, const float* __restrict__ bias,
    float* __restrict__ vout) {
  __shared__ float x[4][256];
  __shared__ float par[2][4][128];
  const int r0 = blockIdx.x * 4;
  const int b  = r0 >> 7;
  const int t  = threadIdx.x;
  const int c  = t & 127;
  const int hf = t >> 7;
  #pragma unroll
  for (int rr = 0; rr < 4; ++rr)
    x[rr][t] = (t < 128) ? vfb[(r0 + rr) * 128 + t]
                         : funkey(poolU[b * 128 + (t - 128)]);
  __syncthreads();
  {
    float a0 = 0.f, a1 = 0.f, a2 = 0.f, a3 = 0.f;
    const int k0 = hf * 128;
    for (int k4 = k0; k4 < k0 + 128; k4 += 4) {
      f4v x0 = *(const f4v*)&x[0][k4];
      f4v x1 = *(const f4v*)&x[1][k4];
      f4v x2 = *(const f4v*)&x[2][k4];
      f4v x3 = *(const f4v*)&x[3][k4];
      #pragma unroll
      for (int u = 0; u < 4; ++u) {
        float wv = W[(k4 + u) * 128 + c];
        a0 += x0[u] * wv; a1 += x1[u] * wv; a2 += x2[u] * wv; a3 += x3[u] * wv;
      }
    }
    par[hf][0][c] = a0; par[hf][1][c] = a1; par[hf][2][c] = a2; par[hf][3][c] = a3;
  }
  __syncthreads();
  if (hf == 0) {
    const float bvv = bias[c];
    #pragma unroll
    for (int rr = 0; rr < 4; ++rr)
      vout[(r0 + rr) * 128 + c] = silu_f(par[0][rr][c] + par[1][rr][c] + bvv);
  }
}

extern "C" void kernel_launch(void* const* d_in, const int* in_sizes, int n_in,
                              void* d_out, int out_size, void* d_ws, size_t ws_size,
                              hipStream_t stream) {
  const float* v_f    = (const float*)d_in[0];
  const float* e_f    = (const float*)d_in[1];
  const float* p_pe   = (const float*)d_in[2];
  const float* t_pe   = (const float*)d_in[3];
  const float* W_vpe  = (const float*)d_in[4];
  const float* b_vpe  = (const float*)d_in[5];
  const float* W_epe  = (const float*)d_in[6];
  const float* b_epe  = (const float*)d_in[7];
  const float* W_ev1  = (const float*)d_in[8];
  const float* b_ev1  = (const float*)d_in[9];
  const float* W_ev2  = (const float*)d_in[10];
  const float* b_ev2  = (const float*)d_in[11];
  const float* W_q    = (const float*)d_in[12];
  const float* b_q    = (const float*)d_in[13];
  const float* W_k    = (const float*)d_in[14];
  const float* b_k    = (const float*)d_in[15];
  const float* W_self = (const float*)d_in[16];
  const float* b_self = (const float*)d_in[17];
  const float* W_out  = (const float*)d_in[18];
  const float* b_out  = (const float*)d_in[19];

  char* ws = (char*)d_ws;
  unsigned short* vb16  = (unsigned short*)(ws + 0);        // 262144
  float*          qbuf  = (float*)(ws + 262144);            // 524288
  float*          kbuf  = (float*)(ws + 786432);            // 524288
  float*          sabuf = (float*)(ws + 1310720);           // 524288
  float*          vfbuf = (float*)(ws + 1835008);           // 524288
  float*          evic  = (float*)(ws + 2359296);           // 524288
  unsigned*       poolU = (unsigned*)(ws + 2883584);        // 4096
  float*          tc    = (float*)(ws + 2887680);           // 4096
  short*          wf1   = (short*)(ws + 2891776);           // 32768
  short*          wf2   = (short*)(ws + 2924544);           // 65536
  short*          wf3   = (short*)(ws + 2990080);           // 32768
  float*          atten = (float*)(ws + 3022848);           // 8388608 -> 11.4MB

  float* v_out = (float*)d_out;
  float* out_e = (float*)d_out + 131072;

  k_front<<<517, 256, 0, stream>>>(W_epe, wf1, W_ev1, wf2, W_ev2, wf3,
                                   t_pe, b_epe, tc, poolU,
                                   v_f, p_pe, W_vpe, b_vpe, W_q, b_q,
                                   W_k, b_k, W_self, b_self, W_ev1, b_ev1,
                                   vb16, qbuf, kbuf, sabuf, evic);
  k_atten<<<512, 256, 0, stream>>>(qbuf, kbuf, atten);
  k_edge<<<1024, 256, 0, stream>>>(e_f, vb16, wf1, wf2, wf3, tc, evic,
                                   b_ev2, atten, sabuf, out_e, vfbuf, poolU);
  k_out<<<256, 256, 0, stream>>>(vfbuf, poolU, W_out, b_out, v_out);
}